// Round 1
// baseline (95.975 us; speedup 1.0000x reference)
//
#include <hip/hip_runtime.h>
#include <hip/hip_bf16.h>

// Embedding gather: out[b,s,:] = weight[x[b,s],:]
//   x:      int32 [B=4, S=2048]          -> 8192 rows
//   weight: fp32  [32000, 512]
//   out:    fp32  [4, 2048, 512]
//
// Pure memory-bound gather. One thread per float4 (16 B/lane — coalescing
// sweet spot). row = tid >> 7 (512/4 = 128 float4 per row), col = tid & 127.
// Consecutive lanes read consecutive float4 within the same gathered row and
// write consecutive float4 of the output row — fully coalesced on both sides.

#define EMB_DIM      512
#define VEC_PER_ROW  (EMB_DIM / 4)   // 128 float4 per row
#define NUM_ROWS     (4 * 2048)      // B * S = 8192
#define TOTAL_VECS   (NUM_ROWS * VEC_PER_ROW)

__global__ __launch_bounds__(256) void embedding_gather_kernel(
    const int* __restrict__ x,
    const float4* __restrict__ weight,   // [32000 * 128] float4
    float4* __restrict__ out)            // [8192 * 128] float4
{
    int tid = blockIdx.x * blockDim.x + threadIdx.x;
    if (tid >= TOTAL_VECS) return;

    int row  = tid >> 7;        // which (b,s) token
    int col4 = tid & 127;       // which float4 within the 512-wide row

    int emb = x[row];           // gathered embedding index (broadcast per 128 threads)
    out[tid] = weight[(long long)emb * VEC_PER_ROW + col4];
}

extern "C" void kernel_launch(void* const* d_in, const int* in_sizes, int n_in,
                              void* d_out, int out_size, void* d_ws, size_t ws_size,
                              hipStream_t stream) {
    const int*    x      = (const int*)d_in[0];
    const float4* weight = (const float4*)d_in[1];
    float4*       out    = (float4*)d_out;

    const int threads = 256;
    const int blocks  = (TOTAL_VECS + threads - 1) / threads;  // 4096
    embedding_gather_kernel<<<blocks, threads, 0, stream>>>(x, weight, out);
}

// Round 3
// 95.564 us; speedup vs baseline: 1.0043x; 1.0043x over previous
//
#include <hip/hip_runtime.h>
#include <hip/hip_bf16.h>

// Embedding gather: out[b,s,:] = weight[x[b,s],:]
//   x:      int32 [B=4, S=2048]          -> 8192 rows
//   weight: fp32  [32000, 512]
//   out:    fp32  [4, 2048, 512]
//
// Pure memory-bound gather: 16 MiB read + 16 MiB write => ~5.3 us at
// 6.3 TB/s achievable. R1 evidence: the bench's 96 us is dominated by
// harness re-poison fills (268 MB @ 42 us each in rocprof top-5); the
// kernel itself is <41 us and likely ~6-10 us.
//
// 2 float4 per thread (ILP, 2048 blocks) + nontemporal output stores
// (out is write-once, never re-read -> don't let it evict gathered
// weight rows from L2; duplicate indices re-hit cache).
// NOTE: __builtin_nontemporal_store needs a NATIVE vector type, not
// HIP's float4 class -> use ext_vector_type(4) float.

typedef float v4f __attribute__((ext_vector_type(4)));

#define EMB_DIM      512
#define VEC_PER_ROW  (EMB_DIM / 4)            // 128 float4 per row
#define NUM_ROWS     (4 * 2048)               // B * S = 8192
#define TOTAL_VECS   (NUM_ROWS * VEC_PER_ROW) // 1048576 float4
#define VECS_PER_BLOCK 512                    // 256 threads x 2 float4

__global__ __launch_bounds__(256) void embedding_gather_kernel(
    const int* __restrict__ x,
    const v4f* __restrict__ weight,   // [32000 * 128] v4f
    v4f* __restrict__ out)            // [8192 * 128] v4f
{
    int v0 = blockIdx.x * VECS_PER_BLOCK + threadIdx.x;  // first float4
    int v1 = v0 + 256;                                   // second float4

    int r0 = v0 >> 7, c0 = v0 & 127;
    int r1 = v1 >> 7, c1 = v1 & 127;

    int e0 = x[r0];                      // L1-broadcast within each 128-group
    int e1 = x[r1];

    v4f a = weight[(size_t)e0 * VEC_PER_ROW + c0];
    v4f b = weight[(size_t)e1 * VEC_PER_ROW + c1];

    __builtin_nontemporal_store(a, &out[v0]);
    __builtin_nontemporal_store(b, &out[v1]);
}

extern "C" void kernel_launch(void* const* d_in, const int* in_sizes, int n_in,
                              void* d_out, int out_size, void* d_ws, size_t ws_size,
                              hipStream_t stream) {
    const int* x      = (const int*)d_in[0];
    const v4f* weight = (const v4f*)d_in[1];
    v4f*       out    = (v4f*)d_out;

    const int threads = 256;
    const int blocks  = TOTAL_VECS / VECS_PER_BLOCK;  // 2048
    embedding_gather_kernel<<<blocks, threads, 0, stream>>>(x, weight, out);
}